// Round 5
// baseline (246.770 us; speedup 1.0000x reference)
//
#include <hip/hip_runtime.h>
#include <math.h>

#define D 2048
#define NE 64
#define NTOK 16384
#define TBLK 64                 /* tokens per block */
#define THREADS 512             /* 8 waves; thread tile 2 tok x 4 exp */
#define CHUNK 64                /* k per staging chunk */
#define NCHUNK (D / CHUNK)      /* 32 */
#define XPAD 66                 /* xT row stride (floats), even for float2 reads */
#define LN_EPS 1e-5f

// ---------------- Kernel A: LayerNorm the expert table, store TRANSPOSED ----------------
__global__ __launch_bounds__(256) void expert_ln_kernel(
    const float* __restrict__ emb, float* __restrict__ eT) {
  const int e = blockIdx.x;
  const int tid = threadIdx.x;
  const float4* row = (const float4*)(emb + (size_t)e * D);
  float4 v0 = row[tid * 2];
  float4 v1 = row[tid * 2 + 1];
  float s = v0.x + v0.y + v0.z + v0.w + v1.x + v1.y + v1.z + v1.w;
  float q = v0.x * v0.x + v0.y * v0.y + v0.z * v0.z + v0.w * v0.w
          + v1.x * v1.x + v1.y * v1.y + v1.z * v1.z + v1.w * v1.w;
  #pragma unroll
  for (int off = 32; off > 0; off >>= 1) {
    s += __shfl_down(s, off);
    q += __shfl_down(q, off);
  }
  __shared__ float red[8];
  const int wid = tid >> 6;
  const int lane = tid & 63;
  if (lane == 0) { red[wid] = s; red[4 + wid] = q; }
  __syncthreads();
  if (tid == 0) {
    red[0] = red[0] + red[1] + red[2] + red[3];
    red[4] = red[4] + red[5] + red[6] + red[7];
  }
  __syncthreads();
  const float mu = red[0] * (1.0f / D);
  const float var = red[4] * (1.0f / D) - mu * mu;
  const float sc = rsqrtf(var + LN_EPS);
  float vals[8] = {v0.x, v0.y, v0.z, v0.w, v1.x, v1.y, v1.z, v1.w};
  const int k0 = tid * 8;
  #pragma unroll
  for (int j = 0; j < 8; ++j) {
    eT[(size_t)(k0 + j) * NE + e] = (vals[j] - mu) * sc;
  }
}

// ---------------- Kernel B: fused GEMM (full K) + token LN + top-2 + softmax ----------------
// Grid: NTOK/TBLK = 256 blocks (1 per CU) x 512 threads.
// Thread (tg=tid>>4, eg=tid&15): tokens {2tg, 2tg+1} x experts {4eg..4eg+3}.
// Inner loop per k: ds_read_b64 (x, 4 addr/wave, 16-way bcast) +
// ds_read_b128 (e, 2-way free) + 8 FMA. Global prefetch one 64-k chunk ahead
// (compute ~2048 cy/chunk >> HBM latency). Epilogue: in-block LN scale +
// 16-lane shfl_xor top-2 merge + 2-way softmax; writes 8 floats per 2 tokens.
__global__ __launch_bounds__(THREADS) void router_fused_kernel(
    const float* __restrict__ x, const float* __restrict__ eT,
    float* __restrict__ out) {
  __shared__ float xT[CHUNK][XPAD];
  __shared__ float eS[CHUNK][NE];
  __shared__ float scs[TBLK];
  const int tid = threadIdx.x;
  const int bt = blockIdx.x;
  const int tg = tid >> 4;          // 0..31: token pair
  const int eg = tid & 15;          // expert group of 4

  // staging coords: x-chunk 64 tok x 64 k; thread loads rows stok, stok+32
  const int stok = tid >> 4;        // 0..31
  const int skq = tid & 15;         // float4 slot (k-offset skq*4)

  float acc[2][4];
  #pragma unroll
  for (int i = 0; i < 2; ++i)
    #pragma unroll
    for (int j = 0; j < 4; ++j) acc[i][j] = 0.f;
  float sA = 0.f, qA = 0.f, sB = 0.f, qB = 0.f;

  const float* xbase = x + (size_t)bt * TBLK * D;
  const float* ebase = eT;

  // preload chunk 0
  float4 px0 = *(const float4*)(xbase + (size_t)stok * D + skq * 4);
  float4 px1 = *(const float4*)(xbase + (size_t)(stok + 32) * D + skq * 4);
  float4 pe0 = *(const float4*)(ebase + (size_t)stok * NE + skq * 4);
  float4 pe1 = *(const float4*)(ebase + (size_t)(stok + 32) * NE + skq * 4);

  for (int c = 0; c < NCHUNK; ++c) {
    __syncthreads();  // all waves done reading LDS for chunk c-1
    // token stats from the registers being staged
    sA += px0.x + px0.y + px0.z + px0.w;
    qA += px0.x * px0.x + px0.y * px0.y + px0.z * px0.z + px0.w * px0.w;
    sB += px1.x + px1.y + px1.z + px1.w;
    qB += px1.x * px1.x + px1.y * px1.y + px1.z * px1.z + px1.w * px1.w;
    // transpose-write x into LDS: xT[k][tok]
    xT[skq * 4 + 0][stok] = px0.x;
    xT[skq * 4 + 1][stok] = px0.y;
    xT[skq * 4 + 2][stok] = px0.z;
    xT[skq * 4 + 3][stok] = px0.w;
    xT[skq * 4 + 0][stok + 32] = px1.x;
    xT[skq * 4 + 1][stok + 32] = px1.y;
    xT[skq * 4 + 2][stok + 32] = px1.z;
    xT[skq * 4 + 3][stok + 32] = px1.w;
    // e chunk rows are contiguous [k][64]
    *(float4*)&eS[stok][skq * 4] = pe0;
    *(float4*)&eS[stok + 32][skq * 4] = pe1;
    // issue next chunk's global loads (consumed next iteration)
    if (c + 1 < NCHUNK) {
      const int off = (c + 1) * CHUNK;
      px0 = *(const float4*)(xbase + (size_t)stok * D + off + skq * 4);
      px1 = *(const float4*)(xbase + (size_t)(stok + 32) * D + off + skq * 4);
      pe0 = *(const float4*)(ebase + (size_t)(off + stok) * NE + skq * 4);
      pe1 = *(const float4*)(ebase + (size_t)(off + stok + 32) * NE + skq * 4);
    }
    __syncthreads();  // chunk c staged
    // compute: 64 k x (2 tok x 4 exp)
    #pragma unroll 16
    for (int kk = 0; kk < CHUNK; ++kk) {
      const float2 a = *(const float2*)&xT[kk][tg * 2];
      const float4 b = *(const float4*)&eS[kk][eg * 4];
      acc[0][0] = fmaf(a.x, b.x, acc[0][0]);
      acc[0][1] = fmaf(a.x, b.y, acc[0][1]);
      acc[0][2] = fmaf(a.x, b.z, acc[0][2]);
      acc[0][3] = fmaf(a.x, b.w, acc[0][3]);
      acc[1][0] = fmaf(a.y, b.x, acc[1][0]);
      acc[1][1] = fmaf(a.y, b.y, acc[1][1]);
      acc[1][2] = fmaf(a.y, b.z, acc[1][2]);
      acc[1][3] = fmaf(a.y, b.w, acc[1][3]);
    }
  }

  // ---- token stats reduction: 16 partial-holders (skq) per token ----
  __syncthreads();
  float* r1 = &xT[0][0];   // [16][64] = 1024 floats (xT has 64*66)
  float* r2 = &eS[0][0];   // [16][64]
  r1[skq * 64 + stok] = sA;
  r1[skq * 64 + stok + 32] = sB;
  r2[skq * 64 + stok] = qA;
  r2[skq * 64 + stok + 32] = qB;
  __syncthreads();
  if (tid < TBLK) {
    float s = 0.f, q = 0.f;
    #pragma unroll
    for (int j = 0; j < 16; ++j) {
      s += r1[j * 64 + tid];
      q += r2[j * 64 + tid];
    }
    const float mu = s * (1.0f / D);
    const float var = q * (1.0f / D) - mu * mu;
    scs[tid] = rsqrtf(var + LN_EPS);   // sim = dot * sc (sum(e_norm)==0)
  }
  __syncthreads();

  const float sc0 = scs[tg * 2];
  const float sc1 = scs[tg * 2 + 1];

  // ---- per-thread top-2 over its 4 experts, for both tokens ----
  float w1[2] = {-INFINITY, -INFINITY}, w2[2] = {-INFINITY, -INFINITY};
  int i1[2] = {0, 0}, i2[2] = {0, 0};
  #pragma unroll
  for (int j = 0; j < 4; ++j) {
    const int e = eg * 4 + j;
    const float v0 = acc[0][j] * sc0;
    const float v1 = acc[1][j] * sc1;
    if (v0 > w1[0]) { w2[0] = w1[0]; i2[0] = i1[0]; w1[0] = v0; i1[0] = e; }
    else if (v0 > w2[0]) { w2[0] = v0; i2[0] = e; }
    if (v1 > w1[1]) { w2[1] = w1[1]; i2[1] = i1[1]; w1[1] = v1; i1[1] = e; }
    else if (v1 > w2[1]) { w2[1] = v1; i2[1] = e; }
  }
  // butterfly merge across the 16 lanes (eg) holding this token pair
  #pragma unroll
  for (int off = 1; off < 16; off <<= 1) {
    #pragma unroll
    for (int i = 0; i < 2; ++i) {
      const float ow1 = __shfl_xor(w1[i], off);
      const float ow2 = __shfl_xor(w2[i], off);
      const int oi1 = __shfl_xor(i1[i], off);
      const int oi2 = __shfl_xor(i2[i], off);
      if (ow1 > w1[i] || (ow1 == w1[i] && oi1 < i1[i])) {
        float nw2; int ni2;
        if (w1[i] > ow2 || (w1[i] == ow2 && i1[i] < oi2)) { nw2 = w1[i]; ni2 = i1[i]; }
        else { nw2 = ow2; ni2 = oi2; }
        w1[i] = ow1; i1[i] = oi1; w2[i] = nw2; i2[i] = ni2;
      } else {
        if (ow1 > w2[i] || (ow1 == w2[i] && oi1 < i2[i])) { w2[i] = ow1; i2[i] = oi1; }
      }
    }
  }

  if (eg == 0) {
    const float invT = 0.02209708691207961f;  // 1/sqrt(2048)
    #pragma unroll
    for (int i = 0; i < 2; ++i) {
      const int t = bt * TBLK + tg * 2 + i;
      const float e1 = expf((w2[i] - w1[i]) * invT);
      const float g1 = 1.0f / (1.0f + e1);
      const float g2 = e1 * g1;
      out[t * 2 + 0] = (float)i1[i];
      out[t * 2 + 1] = (float)i2[i];
      out[2 * NTOK + t * 2 + 0] = g1;
      out[2 * NTOK + t * 2 + 1] = g2;
    }
  }
}

extern "C" void kernel_launch(void* const* d_in, const int* in_sizes, int n_in,
                              void* d_out, int out_size, void* d_ws, size_t ws_size,
                              hipStream_t stream) {
  const float* x = (const float*)d_in[0];     // [4,4096,2048] f32
  const float* emb = (const float*)d_in[1];   // [64,2048] f32
  float* eT = (float*)d_ws;                   // 2048*64 floats = 512 KB
  float* out = (float*)d_out;

  expert_ln_kernel<<<NE, 256, 0, stream>>>(emb, eT);
  router_fused_kernel<<<NTOK / TBLK, THREADS, 0, stream>>>(x, eT, out);
}

// Round 6
// 218.227 us; speedup vs baseline: 1.1308x; 1.1308x over previous
//
#include <hip/hip_runtime.h>
#include <math.h>

typedef __attribute__((ext_vector_type(8))) short short8;
typedef __attribute__((ext_vector_type(8))) unsigned short ushort8;
typedef __attribute__((ext_vector_type(4))) float f32x4;

#define D 2048
#define NE 64
#define NTOK 16384
#define KSPLIT 4
#define KRANGE 512            /* f32 k per block */
#define CF32 16               /* f32 k per chunk */
#define NCHUNK 32             /* KRANGE / CF32 */
#define ASTR 104              /* padded ushort stride per 96-slot row */
#define CHUNK_USH (64 * ASTR) /* 6656 ushorts per B chunk */
#define LN_EPS 1e-5f

// Raw barrier: waits LDS ops only, leaves global loads (vmcnt) in flight.
// __syncthreads would drain vmcnt(0) and kill the prefetch pipeline.
#define BARRIER() asm volatile("s_waitcnt lgkmcnt(0)\n\ts_barrier" ::: "memory")

__device__ __forceinline__ unsigned int bf16rne(float f) {
  unsigned int u = __builtin_bit_cast(unsigned int, f);
  return (u + 0x7fffu + ((u >> 16) & 1u)) >> 16;
}
__device__ __forceinline__ float bf16tof(unsigned int h) {
  return __builtin_bit_cast(float, h << 16);
}

// ---------------- Kernel A: expert LN + 3-way bf16 split, chunk-tiled table ----------------
// B_tiled[(k/16)*64 + e][slot] where slots 6*(k%16)..+5 hold (eh,em,eh,el,em,eh)
// for e's element k. Row stride ASTR=104 (pad vs bank conflicts on frag reads).
__global__ __launch_bounds__(256) void expert_prep_kernel(
    const float* __restrict__ emb, unsigned short* __restrict__ B_tiled) {
  const int e = blockIdx.x;
  const int tid = threadIdx.x;
  const float4* row = (const float4*)(emb + (size_t)e * D);
  float4 v0 = row[tid * 2];
  float4 v1 = row[tid * 2 + 1];
  float s = v0.x + v0.y + v0.z + v0.w + v1.x + v1.y + v1.z + v1.w;
  float q = v0.x * v0.x + v0.y * v0.y + v0.z * v0.z + v0.w * v0.w
          + v1.x * v1.x + v1.y * v1.y + v1.z * v1.z + v1.w * v1.w;
  #pragma unroll
  for (int off = 32; off > 0; off >>= 1) {
    s += __shfl_down(s, off);
    q += __shfl_down(q, off);
  }
  __shared__ float red[8];
  const int wid = tid >> 6;
  const int lane = tid & 63;
  if (lane == 0) { red[wid] = s; red[4 + wid] = q; }
  __syncthreads();
  if (tid == 0) {
    red[0] = red[0] + red[1] + red[2] + red[3];
    red[4] = red[4] + red[5] + red[6] + red[7];
  }
  __syncthreads();
  const float mu = red[0] * (1.0f / D);
  const float var = red[4] * (1.0f / D) - mu * mu;
  const float sc = rsqrtf(var + LN_EPS);
  float vals[8] = {v0.x, v0.y, v0.z, v0.w, v1.x, v1.y, v1.z, v1.w};
  const int k0 = tid * 8;
  #pragma unroll
  for (int j = 0; j < 8; ++j) {
    const int k = k0 + j;
    const float v = (vals[j] - mu) * sc;
    const unsigned int eh = bf16rne(v);
    const float r = v - bf16tof(eh);
    const unsigned int em = bf16rne(r);
    const float r2 = r - bf16tof(em);
    const unsigned int el = bf16rne(r2);
    unsigned int* du = (unsigned int*)(B_tiled +
        ((size_t)(k >> 4) * 64 + e) * ASTR + (k & 15) * 6);
    du[0] = eh | (em << 16);
    du[1] = eh | (el << 16);
    du[2] = em | (eh << 16);
  }
}

// ---------------- Kernel B: K-split bf16-MFMA GEMM + fused token stats ----------------
// Grid: KSPLIT*256 = 1024 blocks x 256 thr (4 waves, 2x2 wave grid).
// Block tile 64 tok x 64 exp; wave tile 32x32 via 4x mfma_f32_16x16x32_bf16.
// Per chunk: stage A (convert f32 -> 6-slot split) + B (flat b128 copy of
// pre-tiled table), raw barriers (vmcnt stays in flight), 3 K-steps of MFMA.
__global__ __launch_bounds__(256, 4) void router_mfma_kernel(
    const float* __restrict__ x, const unsigned short* __restrict__ B_tiled,
    float* __restrict__ dotP, float* __restrict__ sumP,
    float* __restrict__ sumsqP) {
  __shared__ unsigned short A_s[64 * ASTR];
  __shared__ unsigned short B_s[64 * ASTR];
  const int tid = threadIdx.x;
  const int bt = blockIdx.x & 255;
  const int kc = blockIdx.x >> 8;
  const int wid = tid >> 6;
  const int lane = tid & 63;
  const int wr = wid >> 1;          // wave token half
  const int wc = wid & 1;           // wave expert half
  const int l15 = lane & 15;
  const int lh = lane >> 4;
  // A staging: 64 tok x 16 f32-k per chunk = 256 float4; thread -> (tok, kq)
  const int tok = tid >> 2;
  const int kq = tid & 3;

  f32x4 acc00 = {0.f, 0.f, 0.f, 0.f};
  f32x4 acc01 = {0.f, 0.f, 0.f, 0.f};
  f32x4 acc10 = {0.f, 0.f, 0.f, 0.f};
  f32x4 acc11 = {0.f, 0.f, 0.f, 0.f};
  float s1 = 0.f, q1 = 0.f;

  const float* xbase = x + ((size_t)bt * 64 + tok) * D + kc * KRANGE + kq * 4;
  const unsigned short* btab = B_tiled + (size_t)kc * NCHUNK * CHUNK_USH;

  // prologue: chunk 0 loads
  float4 px = *(const float4*)(xbase);
  ushort8 pb0 = *(const ushort8*)(btab + tid * 8);
  ushort8 pb1 = *(const ushort8*)(btab + (tid + 256) * 8);
  ushort8 pb2 = *(const ushort8*)(btab + (tid + 512) * 8);
  ushort8 pb3 = {0, 0, 0, 0, 0, 0, 0, 0};
  if (tid < 64) pb3 = *(const ushort8*)(btab + (tid + 768) * 8);

  const int arow0 = (wr * 32 + l15) * ASTR + lh * 8;
  const int arow1 = arow0 + 16 * ASTR;
  const int brow0 = (wc * 32 + l15) * ASTR + lh * 8;
  const int brow1 = brow0 + 16 * ASTR;

  for (int c = 0; c < NCHUNK; ++c) {
    BARRIER();  // all waves done reading LDS for chunk c-1 (lgkm only)
    // ---- stage A: convert + 6-slot split write ----
    {
      float xv[4] = {px.x, px.y, px.z, px.w};
      unsigned int* au = (unsigned int*)A_s;
      const int base_u = tok * 52 + kq * 12;  // (tok*ASTR + kq*4*6) / 2
      #pragma unroll
      for (int j = 0; j < 4; ++j) {
        const float v = xv[j];
        s1 += v;
        q1 += v * v;
        const unsigned int xh = bf16rne(v);
        const float r = v - bf16tof(xh);
        const unsigned int xm = bf16rne(r);
        const float r2 = r - bf16tof(xm);
        const unsigned int xl = bf16rne(r2);
        au[base_u + j * 3 + 0] = xh | (xh << 16);
        au[base_u + j * 3 + 1] = xm | (xh << 16);
        au[base_u + j * 3 + 2] = xm | (xl << 16);
      }
    }
    // ---- stage B: flat conflict-free b128 copy ----
    *(ushort8*)&B_s[tid * 8] = pb0;
    *(ushort8*)&B_s[(tid + 256) * 8] = pb1;
    *(ushort8*)&B_s[(tid + 512) * 8] = pb2;
    if (tid < 64) *(ushort8*)&B_s[(tid + 768) * 8] = pb3;
    // ---- prefetch chunk c+1 (stays in flight across raw barrier) ----
    if (c + 1 < NCHUNK) {
      px = *(const float4*)(xbase + (c + 1) * CF32);
      const unsigned short* bsrc = btab + (size_t)(c + 1) * CHUNK_USH;
      pb0 = *(const ushort8*)(bsrc + tid * 8);
      pb1 = *(const ushort8*)(bsrc + (tid + 256) * 8);
      pb2 = *(const ushort8*)(bsrc + (tid + 512) * 8);
      if (tid < 64) pb3 = *(const ushort8*)(bsrc + (tid + 768) * 8);
    }
    BARRIER();  // chunk c staged
    // ---- compute: 3 MFMA K-steps over the 96 bf16-K slots ----
    #pragma unroll
    for (int ks = 0; ks < 3; ++ks) {
      const int kk = ks * 32;
      const short8 a0 = *(const short8*)&A_s[arow0 + kk];
      const short8 a1 = *(const short8*)&A_s[arow1 + kk];
      const short8 b0 = *(const short8*)&B_s[brow0 + kk];
      const short8 b1 = *(const short8*)&B_s[brow1 + kk];
      acc00 = __builtin_amdgcn_mfma_f32_16x16x32_bf16(a0, b0, acc00, 0, 0, 0);
      acc01 = __builtin_amdgcn_mfma_f32_16x16x32_bf16(a0, b1, acc01, 0, 0, 0);
      acc10 = __builtin_amdgcn_mfma_f32_16x16x32_bf16(a1, b0, acc10, 0, 0, 0);
      acc11 = __builtin_amdgcn_mfma_f32_16x16x32_bf16(a1, b1, acc11, 0, 0, 0);
    }
  }

  // ---- dot partials: [kc][token][expert]; C/D map col=lane&15 row=(lane>>4)*4+reg ----
  {
    float* dp = dotP + ((size_t)kc * NTOK + (size_t)bt * 64) * NE;
    const int rbase0 = wr * 32 + lh * 4;
    const int cbase = wc * 32 + l15;
    #pragma unroll
    for (int r = 0; r < 4; ++r) {
      dp[(rbase0 + r) * NE + cbase] = acc00[r];
      dp[(rbase0 + r) * NE + cbase + 16] = acc01[r];
      dp[(rbase0 + 16 + r) * NE + cbase] = acc10[r];
      dp[(rbase0 + 16 + r) * NE + cbase + 16] = acc11[r];
    }
  }

  // ---- token stats reduction (4 kq-partials per token) ----
  BARRIER();  // frag reads done; A_s reusable
  float* fl = (float*)A_s;
  fl[kq * 64 + tok] = s1;
  fl[256 + kq * 64 + tok] = q1;
  BARRIER();
  if (tid < 64) {
    const float ssum = fl[tid] + fl[64 + tid] + fl[128 + tid] + fl[192 + tid];
    const float qsum = fl[256 + tid] + fl[320 + tid] + fl[384 + tid] + fl[448 + tid];
    const int gt = bt * 64 + tid;
    sumP[kc * NTOK + gt] = ssum;
    sumsqP[kc * NTOK + gt] = qsum;
  }
}

// ---------------- Kernel C: reduce partials, top-2, softmax gates ----------------
__global__ __launch_bounds__(256) void finalize_kernel(
    const float* __restrict__ dotP, const float* __restrict__ sumP,
    const float* __restrict__ sumsqP, float* __restrict__ out) {
  const int tid = threadIdx.x;
  const int t = blockIdx.x * 32 + (tid >> 3);
  const int l8 = tid & 7;

  float s1 = 0.f, s2 = 0.f;
  #pragma unroll
  for (int kc = 0; kc < KSPLIT; ++kc) {
    s1 += sumP[kc * NTOK + t];
    s2 += sumsqP[kc * NTOK + t];
  }
  const float mu = s1 * (1.0f / D);
  const float var = s2 * (1.0f / D) - mu * mu;
  const float sc = rsqrtf(var + LN_EPS);  // sim = dot * sc (sum(e_norm)==0)

  float d[8] = {0.f, 0.f, 0.f, 0.f, 0.f, 0.f, 0.f, 0.f};
  #pragma unroll
  for (int kc = 0; kc < KSPLIT; ++kc) {
    const float* dp = dotP + ((size_t)kc * NTOK + t) * NE + l8 * 8;
    float4 a = *(const float4*)dp;
    float4 b = *(const float4*)(dp + 4);
    d[0] += a.x; d[1] += a.y; d[2] += a.z; d[3] += a.w;
    d[4] += b.x; d[5] += b.y; d[6] += b.z; d[7] += b.w;
  }

  float w1 = -INFINITY, w2 = -INFINITY;
  int i1 = 0, i2 = 0;
  #pragma unroll
  for (int j = 0; j < 8; ++j) {
    const float v = d[j] * sc;
    const int e = l8 * 8 + j;
    if (v > w1) { w2 = w1; i2 = i1; w1 = v; i1 = e; }
    else if (v > w2) { w2 = v; i2 = e; }
  }
  #pragma unroll
  for (int off = 1; off < 8; off <<= 1) {
    const float ow1 = __shfl_xor(w1, off);
    const float ow2 = __shfl_xor(w2, off);
    const int oi1 = __shfl_xor(i1, off);
    const int oi2 = __shfl_xor(i2, off);
    if (ow1 > w1 || (ow1 == w1 && oi1 < i1)) {
      float nw2; int ni2;
      if (w1 > ow2 || (w1 == ow2 && i1 < oi2)) { nw2 = w1; ni2 = i1; }
      else { nw2 = ow2; ni2 = oi2; }
      w1 = ow1; i1 = oi1; w2 = nw2; i2 = ni2;
    } else {
      if (ow1 > w2 || (ow1 == w2 && oi1 < i2)) { w2 = ow1; i2 = oi1; }
    }
  }

  if (l8 == 0) {
    const float invT = 0.02209708691207961f;  // 1/sqrt(2048)
    const float e1 = expf((w2 - w1) * invT);
    const float g1 = 1.0f / (1.0f + e1);
    const float g2 = e1 * g1;
    out[t * 2 + 0] = (float)i1;
    out[t * 2 + 1] = (float)i2;
    out[2 * NTOK + t * 2 + 0] = g1;
    out[2 * NTOK + t * 2 + 1] = g2;
  }
}

extern "C" void kernel_launch(void* const* d_in, const int* in_sizes, int n_in,
                              void* d_out, int out_size, void* d_ws, size_t ws_size,
                              hipStream_t stream) {
  const float* x = (const float*)d_in[0];     // [4,4096,2048] f32
  const float* emb = (const float*)d_in[1];   // [64,2048] f32
  unsigned short* B_tiled = (unsigned short*)d_ws;            // 128*64*104 ush = 1.7 MB
  float* dotP = (float*)((char*)d_ws + 2 * 1024 * 1024);      // 4*16384*64 f = 16.8 MB
  float* sumP = dotP + (size_t)KSPLIT * NTOK * NE;
  float* sumsqP = sumP + (size_t)KSPLIT * NTOK;
  float* out = (float*)d_out;

  expert_prep_kernel<<<NE, 256, 0, stream>>>(emb, B_tiled);
  router_mfma_kernel<<<KSPLIT * 256, 256, 0, stream>>>(x, B_tiled, dotP, sumP, sumsqP);
  finalize_kernel<<<NTOK / 32, 256, 0, stream>>>(dotP, sumP, sumsqP, out);
}